// Round 3
// baseline (253.899 us; speedup 1.0000x reference)
//
#include <hip/hip_runtime.h>

// ---------------------------------------------------------------------------
// Block-sparse linear  y = x @ W^T + bias  on MI355X (gfx950)
// Round 5: BARRIER-FREE, LDS-FREE main kernel. Rounds 2-4 showed every
// LDS+__syncthreads structure is stuck at MfmaUtil <= 22% (58/95/77 us):
// __syncthreads drains vmcnt(0), so each step exposes full L2 latency, and
// r4's 2-bit swizzle added 4-way bank conflicts (6.29M cycles).
// Fix: the mfma_f32_16x16x32_bf16 fragment layout (lane = row l&15, k-chunk
// l>>4, 8 contiguous bf16) IS a coalesced 16B/lane global load from
// row-major bf16 (16 rows x 128B = full cache lines). So each wave loads
// fragments STRAIGHT from global (L1/L2) into registers and MFMAs:
//   - no barriers, no LDS, no bank conflicts
//   - latency hidden by a 1-deep register pipeline (F0/F1 frag buffers)
//   - wave = 64 rows x 64 cols (acc[4][4]); wg = 4 waves = 256 rows
//   - B block (8KB) read by all 4 waves of the wg -> L1 absorbs the dup
//   - grid 16 nt x 64 rb = 1024 wgs, LPT (heavy rb first), XCD-aware decode
//     (each XCD owns 2 x-panels = 4MB ~= its private L2)
// Per wave per block-step: 16 coalesced global_load_dwordx4 + 32 MFMA.
// Predicted: main 30-38us, MfmaUtil 45-60%, bank conflicts 0, VGPR ~220.
// ---------------------------------------------------------------------------

typedef __attribute__((ext_vector_type(8))) short bf16x8;   // MFMA A/B frag
typedef __attribute__((ext_vector_type(8))) unsigned short u16x8;
typedef __attribute__((ext_vector_type(4))) float f32x4;     // MFMA C/D frag

#define N_ROWS 4096
#define IN_DIM 4096
#define OUT_DIM 4096
#define K_BLOCKS 1024
#define NT 256            // rows per workgroup (4 waves x 64 rows)
#define PK_STRIDE 256     // max blocks per row-block we store (realistic max ~35)

// fp32 -> bf16 round-to-nearest-even
__device__ static inline unsigned short f2bf(float f) {
    unsigned u = __float_as_uint(f);
    u += 0x7FFFu + ((u >> 16) & 1u);
    return (unsigned short)(u >> 16);
}

// --- prep: convert x (16M f32) + blocks (4M f32) to bf16, AND build CSR ----
// Blocks 0..10239 convert (each thread 8 floats); block 10240 builds the
// CSR + descending-count (LPT) schedule. Unchanged from r4 (verified).
__global__ void bsl_prep(const float* __restrict__ x,
                         const float* __restrict__ blocks,
                         unsigned short* __restrict__ xb,
                         unsigned short* __restrict__ bb,
                         const int* __restrict__ row_idx,
                         const int* __restrict__ col_idx,
                         int* __restrict__ counts,
                         int* __restrict__ sched,
                         int* __restrict__ csr_pk) {
    if (blockIdx.x == 10240) {
        __shared__ int cnt_s[64];
        __shared__ int sorted_s[64];
        const int t = threadIdx.x;
        if (t < 64) cnt_s[t] = 0;
        __syncthreads();
#pragma unroll
        for (int i = 0; i < 4; ++i) {
            const int k = t + i * 256;           // 0..1023
            const int r = row_idx[k];
            const int rank = atomicAdd(&cnt_s[r], 1);
            if (rank < PK_STRIDE) csr_pk[r * PK_STRIDE + rank] = (k << 6) | col_idx[k];
        }
        __syncthreads();
        if (t < 64) {
            const int mc = cnt_s[t];
            counts[t] = mc;
            int pos = 0;
            for (int j = 0; j < 64; ++j) {
                const int cj = cnt_s[j];
                pos += (cj > mc || (cj == mc && j < t)) ? 1 : 0;
            }
            sorted_s[pos] = t;                   // descending by count
        }
        __syncthreads();
        if (t < 64) sched[t] = sorted_s[t];      // heavy row-blocks first (LPT)
        return;
    }
    // ---- convert ----
    long t = (long)blockIdx.x * 256 + threadIdx.x;   // 0 .. 2621439 (8 floats each)
    const float4* src;
    unsigned short* dst;
    long off4;
    if (t < 2097152) {            // x region
        src = (const float4*)x;  dst = xb;  off4 = t * 2;
    } else {                      // blocks region
        src = (const float4*)blocks;  dst = bb;  off4 = (t - 2097152) * 2;
    }
    float4 a = src[off4];
    float4 b = src[off4 + 1];
    u16x8 v;
    v[0] = f2bf(a.x); v[1] = f2bf(a.y); v[2] = f2bf(a.z); v[3] = f2bf(a.w);
    v[4] = f2bf(b.x); v[5] = f2bf(b.y); v[6] = f2bf(b.z); v[7] = f2bf(b.w);
    *(u16x8*)(dst + off4 * 4) = v;
}

// --- main: barrier-free direct-global MFMA --------------------------------
// Fragment addressing (harness-verified layout from r1-r4):
//   af[r][s]: lane (m,q) <- xb[(n0 + w*64 + r*16 + m)*4096 + ci*64 + s*32 + q*8]
//   bf[c][s]: lane (m,q) <- blk[k*4096 + (c*16 + m)*64 + s*32 + q*8]
// Each load instr: 16 rows x 64B segments; the s=0/s=1 pair completes each
// 128B line -> 100% line utilization. acc C/D layout: col=lane&15, row=q*4+e.
__global__ __launch_bounds__(256, 2) void bsl_main(
    const unsigned short* __restrict__ xb,   // [4096][4096] bf16
    const unsigned short* __restrict__ blk,  // [1024][64][64] bf16
    const float* __restrict__ bias,
    const int* __restrict__ counts,
    const int* __restrict__ sched,
    const int* __restrict__ csr_pk,
    float* __restrict__ y) {

    const int tid = threadIdx.x;
    const int w = tid >> 6;        // wave 0..3 -> rows [w*64, w*64+64)
    const int l = tid & 63;
    const int m = l & 15;          // MFMA lane coord (row within 16-row group)
    const int q = l >> 4;          // k-chunk (8 bf16) within 32-k half

    // XCD-aware decode: consecutive bids round-robin the 8 XCDs; XCD x owns
    // nt in {2x, 2x+1} for ALL rb ranks -> its 2 x-panels (4MB bf16) stay in
    // its private 4MB L2. rbrank ascending = heavy-first (LPT).
    const int bid = blockIdx.x;            // 0..1023
    const int xcd = bid & 7;
    const int idx = bid >> 3;              // 0..127
    const int nt  = xcd * 2 + (idx & 1);   // 0..15
    const int rbrank = idx >> 1;           // 0..63
    const int rb  = sched[rbrank];
    const int cnt = counts[rb];
    const int n0  = nt * NT;

    // lane-constant base pointers
    const unsigned short* xlane =
        xb + (size_t)(n0 + w * 64 + m) * IN_DIM + q * 8;
    const unsigned short* blane = blk + m * 64 + q * 8;
    const int* pkp = csr_pk + rb * PK_STRIDE;

    f32x4 acc[4][4];
#pragma unroll
    for (int r = 0; r < 4; ++r)
#pragma unroll
        for (int c = 0; c < 4; ++c) acc[r][c] = (f32x4){0.f, 0.f, 0.f, 0.f};

    // two named fragment buffers (static indices only -- rule #20)
    bf16x8 a0[4][2], b0[4][2], a1[4][2], b1[4][2];

    auto loadF = [&](bf16x8 (&A)[4][2], bf16x8 (&B)[4][2], int pk) {
        const int k  = pk >> 6;
        const int ci = pk & 63;
        const unsigned short* ap = xlane + ci * 64;
        const unsigned short* bp = blane + (size_t)k * 4096;
#pragma unroll
        for (int r = 0; r < 4; ++r)
#pragma unroll
            for (int s = 0; s < 2; ++s)
                A[r][s] = *(const bf16x8*)(ap + (size_t)(r * 16) * IN_DIM + s * 32);
#pragma unroll
        for (int c = 0; c < 4; ++c)
#pragma unroll
            for (int s = 0; s < 2; ++s)
                B[c][s] = *(const bf16x8*)(bp + c * 1024 + s * 32);
    };

    auto computeF = [&](bf16x8 (&A)[4][2], bf16x8 (&B)[4][2]) {
#pragma unroll
        for (int s = 0; s < 2; ++s)
#pragma unroll
            for (int r = 0; r < 4; ++r)
#pragma unroll
                for (int c = 0; c < 4; ++c)
                    acc[r][c] = __builtin_amdgcn_mfma_f32_16x16x32_bf16(
                        A[r][s], B[c][s], acc[r][c], 0, 0, 0);
    };

    // ---- 1-deep register pipeline: loads for block j+1 are in flight while
    //      MFMAs for block j run. No barriers anywhere.
    if (cnt > 0) {
        loadF(a0, b0, pkp[0]);
        for (int j = 0; j < cnt - 1; j += 2) {
            loadF(a1, b1, pkp[j + 1]);
            computeF(a0, b0);
            if (j + 2 < cnt) loadF(a0, b0, pkp[j + 2]);
            computeF(a1, b1);
        }
        if (cnt & 1) computeF(a0, b0);
    }

    // epilogue: C/D layout col=lane&15, row=q*4+e (harness-verified r1-r4);
    // cnt==0 row-blocks write bias only (acc stays zero).
    const int colbase = rb * 64;
#pragma unroll
    for (int c = 0; c < 4; ++c) {
        const float bv = bias[colbase + c * 16 + m];
#pragma unroll
        for (int r = 0; r < 4; ++r) {
            const int rowb = n0 + w * 64 + r * 16 + q * 4;
#pragma unroll
            for (int e = 0; e < 4; ++e) {
                y[(size_t)(rowb + e) * OUT_DIM + colbase + c * 16 + m] =
                    acc[r][c][e] + bv;
            }
        }
    }
}

// ---------------------------------------------------------------------------
extern "C" void kernel_launch(void* const* d_in, const int* in_sizes, int n_in,
                              void* d_out, int out_size, void* d_ws, size_t ws_size,
                              hipStream_t stream) {
    const float* x      = (const float*)d_in[0];
    const float* blocks = (const float*)d_in[1];
    const float* bias   = (const float*)d_in[2];
    const int* row_idx  = (const int*)d_in[3];
    const int* col_idx  = (const int*)d_in[4];
    float* y = (float*)d_out;

    // ws layout: x_bf16 (32MB) | blocks_bf16 (8MB) | counts(64) | sched(64) |
    //            pad | csr_pk (64*PK_STRIDE ints)
    const size_t base = 41943040u;   // 40 MB
    unsigned short* xb = (unsigned short*)d_ws;
    unsigned short* bb = xb + (size_t)N_ROWS * IN_DIM;
    int* counts = (int*)((char*)d_ws + base);
    int* sched  = counts + 64;
    int* csr_pk = (int*)((char*)d_ws + base + 1024);
    if (ws_size < base + 1024 + (size_t)64 * PK_STRIDE * 4) return;

    hipLaunchKernelGGL(bsl_prep, dim3(10241), dim3(256), 0, stream,
                       x, blocks, xb, bb, row_idx, col_idx, counts, sched, csr_pk);
    hipLaunchKernelGGL(bsl_main, dim3(1024), dim3(256), 0, stream,
                       xb, bb, bias, counts, sched, csr_pk, y);
}

// Round 4
// 214.973 us; speedup vs baseline: 1.1811x; 1.1811x over previous
//
#include <hip/hip_runtime.h>

// ---------------------------------------------------------------------------
// Block-sparse linear  y = x @ W^T + bias  on MI355X (gfx950)
// Round 6: r2 geometry (NT=128, 256thr, acc[2][4], pair schedule, 4 wgs/CU)
// + two targeted changes:
//  (1) A bypasses LDS (zero intra-wg reuse): 4 coalesced global bf16x8 loads
//      per wave per step, double-buffered in 32 VGPRs (aA/aB). Only B (4x
//      reuse across waves) goes through LDS, double-buffered: 16KB total.
//      LDS traffic per step: 72KB -> 40KB.
//  (2) Counted vmcnt (T4), never vmcnt(0) in-loop: raw s_barrier + asm
//      s_waitcnt vmcnt(6) so next step's B-stage + A-loads stay in flight
//      across both barriers. r2/r3/r4 all used __syncthreads (= vmcnt(0)
//      drain every step) -- the documented anti-pattern.
// Count derivation (issue order pinned by "memory"-clobber asm):
//   per step j: [stageB(j) 2] ... [loadA(j) 4][stageB(j+1) 2] -> wait point:
//   newer-than-stageB(j) = 6 -> vmcnt(6); tail/no-next paths: 4.
// Ledger: r2=58us(2 drains/step), r3=95(fat wg), r4=77(conflicts+drains),
// r5=132(no LDS, VGPR collapse). Non-main time ~121-128us constant.
// ---------------------------------------------------------------------------

typedef __attribute__((ext_vector_type(8))) short bf16x8;   // MFMA A/B frag
typedef __attribute__((ext_vector_type(8))) unsigned short u16x8;
typedef __attribute__((ext_vector_type(4))) float f32x4;     // MFMA C/D frag

#define N_ROWS 4096
#define IN_DIM 4096
#define OUT_DIM 4096
#define K_BLOCKS 1024
#define NT 128            // rows per workgroup (4 waves x 32 rows)
#define PK_STRIDE 256     // max blocks per row-block we store (realistic max ~35)

// fp32 -> bf16 round-to-nearest-even
__device__ static inline unsigned short f2bf(float f) {
    unsigned u = __float_as_uint(f);
    u += 0x7FFFu + ((u >> 16) & 1u);
    return (unsigned short)(u >> 16);
}

__device__ static inline void async_copy16(const void* g, void* l) {
    __builtin_amdgcn_global_load_lds(
        (const __attribute__((address_space(1))) void*)g,
        (__attribute__((address_space(3))) void*)l, 16, 0, 0);
}

// --- prep: convert x (16M f32) + blocks (4M f32) to bf16, AND build CSR ----
// Blocks 0..10239 convert (each thread 8 floats); block 10240 builds the
// CSR + descending-count schedule. Unchanged from r4/r5 (verified).
__global__ void bsl_prep(const float* __restrict__ x,
                         const float* __restrict__ blocks,
                         unsigned short* __restrict__ xb,
                         unsigned short* __restrict__ bb,
                         const int* __restrict__ row_idx,
                         const int* __restrict__ col_idx,
                         int* __restrict__ counts,
                         int* __restrict__ sched,
                         int* __restrict__ csr_pk) {
    if (blockIdx.x == 10240) {
        __shared__ int cnt_s[64];
        __shared__ int sorted_s[64];
        const int t = threadIdx.x;
        if (t < 64) cnt_s[t] = 0;
        __syncthreads();
#pragma unroll
        for (int i = 0; i < 4; ++i) {
            const int k = t + i * 256;           // 0..1023
            const int r = row_idx[k];
            const int rank = atomicAdd(&cnt_s[r], 1);
            if (rank < PK_STRIDE) csr_pk[r * PK_STRIDE + rank] = (k << 6) | col_idx[k];
        }
        __syncthreads();
        if (t < 64) {
            const int mc = cnt_s[t];
            counts[t] = mc;
            int pos = 0;
            for (int j = 0; j < 64; ++j) {
                const int cj = cnt_s[j];
                pos += (cj > mc || (cj == mc && j < t)) ? 1 : 0;
            }
            sorted_s[pos] = t;                   // descending by count
        }
        __syncthreads();
        if (t < 64) sched[t] = sorted_s[t];
        return;
    }
    // ---- convert ----
    long t = (long)blockIdx.x * 256 + threadIdx.x;   // 0 .. 2621439 (8 floats each)
    const float4* src;
    unsigned short* dst;
    long off4;
    if (t < 2097152) {            // x region
        src = (const float4*)x;  dst = xb;  off4 = t * 2;
    } else {                      // blocks region
        src = (const float4*)blocks;  dst = bb;  off4 = (t - 2097152) * 2;
    }
    float4 a = src[off4];
    float4 b = src[off4 + 1];
    u16x8 v;
    v[0] = f2bf(a.x); v[1] = f2bf(a.y); v[2] = f2bf(a.z); v[3] = f2bf(a.w);
    v[4] = f2bf(b.x); v[5] = f2bf(b.y); v[6] = f2bf(b.z); v[7] = f2bf(b.w);
    *(u16x8*)(dst + off4 * 4) = v;
}

// --- main ------------------------------------------------------------------
// B LDS swizzle (r2-verified, 0 conflicts): 64x64 bf16 tile, row = 128B = 8
// 16B-chunks; phys chunk p of row r holds logical chunk p ^ (r&7). Staging
// pre-swizzles the GLOBAL source (global_load_lds dest must be linear);
// read side: cc = (s*4+q) ^ (m&7) -- consecutive 8 lanes cover all 8 chunks.
// A fragment (direct global, layout harness-verified r5):
//   A[r][s]: lane (m,q) <- xb[(n0+w*32+r*16+m)*4096 + ci*64 + s*32 + q*8]
__global__ __launch_bounds__(256, 4) void bsl_main(
    const unsigned short* __restrict__ xb,   // [4096][4096] bf16
    const unsigned short* __restrict__ blk,  // [1024][64][64] bf16
    const float* __restrict__ bias,
    const int* __restrict__ counts,
    const int* __restrict__ sched,
    const int* __restrict__ csr_pk,
    float* __restrict__ y) {
    __shared__ unsigned short b_lds[2][64 * 64];   // 2 x 8 KB

    const int tid = threadIdx.x;
    const int w = tid >> 6;        // wave 0..3 -> rows [w*32, w*32+32)
    const int l = tid & 63;
    const int m = l & 15;          // MFMA lane coord
    const int q = l >> 4;          // quad (k-chunk)

    const int nt = blockIdx.x;     // 32 n-tiles of 128 rows
    const int p  = blockIdx.y;     // 32 pairs (rank p with rank 63-p)
    const int n0 = nt * NT;

    const int rb0  = sched[p];
    const int rb1  = sched[63 - p];
    const int cnt0 = counts[rb0];
    const int cnt1 = counts[rb1];
    const int total = cnt0 + cnt1;

    // B staging constants (pre-swizzled global source)
    const int srow = l >> 3;                    // 0..7
    const int scc  = (l & 7) ^ srow;            // swizzled col-chunk
    const int xorv = m & 7;                     // read-side swizzle

    // A per-lane base
    const unsigned short* xlane =
        xb + (size_t)(n0 + w * 32 + m) * IN_DIM + q * 8;
    const int* pk0p = csr_pk + rb0 * PK_STRIDE;
    const int* pk1p = csr_pk + rb1 * PK_STRIDE;

    f32x4 acc[2][4];
#pragma unroll
    for (int r = 0; r < 2; ++r)
#pragma unroll
        for (int c = 0; c < 4; ++c) acc[r][c] = (f32x4){0.f, 0.f, 0.f, 0.f};

    auto fetch_pk = [&](int i) -> int {
        return (i < cnt0) ? pk0p[i] : pk1p[i - cnt0];
    };

    // stage B tile (8KB = 8 chunks of 1KB); wave w stages chunks {w, w+4}
    auto stageB = [&](int buf, int k) {
        const unsigned short* src = blk + (size_t)k * 4096 + srow * 64 + scc * 8;
        unsigned short* dst = &b_lds[buf][0];
#pragma unroll
        for (int i = 0; i < 2; ++i) {
            const int ch = i * 4 + w;
            async_copy16(src + ch * 512, dst + ch * 512);
        }
    };

    // A fragments straight global -> regs (4 coalesced 16B/lane loads)
    auto loadA = [&](bf16x8 (&A)[2][2], int ci) {
        const unsigned short* ap = xlane + ci * 64;
#pragma unroll
        for (int r = 0; r < 2; ++r)
#pragma unroll
            for (int s = 0; s < 2; ++s)
                A[r][s] = *(const bf16x8*)(ap + (size_t)(r * 16) * IN_DIM + s * 32);
    };

    auto compute = [&](int buf, bf16x8 (&A)[2][2]) {
        bf16x8 bfr[4][2];
#pragma unroll
        for (int c = 0; c < 4; ++c)
#pragma unroll
            for (int s = 0; s < 2; ++s) {
                const int cc = (s * 4 + q) ^ xorv;
                bfr[c][s] = *(const bf16x8*)(&b_lds[buf][(c * 16 + m) * 64 + cc * 8]);
            }
        __builtin_amdgcn_s_setprio(1);
#pragma unroll
        for (int s = 0; s < 2; ++s)
#pragma unroll
            for (int r = 0; r < 2; ++r)
#pragma unroll
                for (int c = 0; c < 4; ++c)
                    acc[r][c] = __builtin_amdgcn_mfma_f32_16x16x32_bf16(
                        A[r][s], bfr[c][s], acc[r][c], 0, 0, 0);
        __builtin_amdgcn_s_setprio(0);
    };

    // epilogue: C/D layout col=lane&15, row=q*4+e (harness-verified r1-r5)
    auto epilogue = [&](int rb) {
        const int colbase = rb * 64;
#pragma unroll
        for (int c = 0; c < 4; ++c) {
            const float bv = bias[colbase + c * 16 + m];
#pragma unroll
            for (int r = 0; r < 2; ++r) {
                const int rowb = n0 + w * 32 + r * 16 + q * 4;
#pragma unroll
                for (int e = 0; e < 4; ++e) {
                    y[(size_t)(rowb + e) * OUT_DIM + colbase + c * 16 + m] =
                        acc[r][c][e] + bv;
                }
            }
        }
    };
    auto zacc = [&]() {
#pragma unroll
        for (int r = 0; r < 2; ++r)
#pragma unroll
            for (int c = 0; c < 4; ++c) acc[r][c] = (f32x4){0.f, 0.f, 0.f, 0.f};
    };

    if (cnt0 == 0) epilogue(rb0);          // bias-only row-block

    bf16x8 aA[2][2], aB[2][2];

    // prologue: stage B(0) then A(0) -- order pinned so vmcnt counts hold
    if (total > 0) {
        const int pkA = fetch_pk(0);
        stageB(0, pkA >> 6);
        asm volatile("" ::: "memory");     // pin issue order: B(0) before A(0)
        loadA(aA, pkA & 63);
    }
    int pkN = (total > 1) ? fetch_pk(1) : 0;

    // ---- main loop, unrolled x2 (static A-buffer alternation, rule #20).
    // All barrier-containing branches depend only on wg-uniform values.
    int j = 0;
    while (j + 2 <= total) {
        // ---- step j: compute buf0/aA; prefetch (j+1) into buf1/aB
        stageB(1, pkN >> 6);
        asm volatile("s_waitcnt vmcnt(6)\n\ts_barrier" ::: "memory"); // B(j) in LDS
        loadA(aB, pkN & 63);
        const int pk2 = (j + 2 < total) ? fetch_pk(j + 2) : 0;
        compute(0, aA);
        if (j == cnt0 - 1) { epilogue(rb0); zacc(); }
        asm volatile("s_waitcnt lgkmcnt(0)\n\ts_barrier" ::: "memory"); // buf0 reads done
        // ---- step j+1: compute buf1/aB; prefetch (j+2) into buf0/aA
        if (j + 2 < total) {
            stageB(0, pk2 >> 6);
            asm volatile("s_waitcnt vmcnt(6)\n\ts_barrier" ::: "memory"); // B(j+1) ready
            loadA(aA, pk2 & 63);
            pkN = (j + 3 < total) ? fetch_pk(j + 3) : 0;
        } else {
            asm volatile("s_waitcnt vmcnt(4)\n\ts_barrier" ::: "memory"); // only A(j+1) newer
        }
        compute(1, aB);
        if (j + 1 == cnt0 - 1) { epilogue(rb0); zacc(); }
        asm volatile("s_waitcnt lgkmcnt(0)\n\ts_barrier" ::: "memory"); // buf1 reads done
        j += 2;
    }
    if (j < total) {                       // tail step (total odd): buf0/aA
        asm volatile("s_waitcnt vmcnt(4)\n\ts_barrier" ::: "memory");
        compute(0, aA);
        if (j == cnt0 - 1) { epilogue(rb0); zacc(); }
    }

    epilogue(rb1);                         // bias-only if cnt1 == 0
}

// ---------------------------------------------------------------------------
extern "C" void kernel_launch(void* const* d_in, const int* in_sizes, int n_in,
                              void* d_out, int out_size, void* d_ws, size_t ws_size,
                              hipStream_t stream) {
    const float* x      = (const float*)d_in[0];
    const float* blocks = (const float*)d_in[1];
    const float* bias   = (const float*)d_in[2];
    const int* row_idx  = (const int*)d_in[3];
    const int* col_idx  = (const int*)d_in[4];
    float* y = (float*)d_out;

    // ws layout: x_bf16 (32MB) | blocks_bf16 (8MB) | counts(64) | sched(64) |
    //            pad | csr_pk (64*PK_STRIDE ints)
    const size_t base = 41943040u;   // 40 MB
    unsigned short* xb = (unsigned short*)d_ws;
    unsigned short* bb = xb + (size_t)N_ROWS * IN_DIM;
    int* counts = (int*)((char*)d_ws + base);
    int* sched  = counts + 64;
    int* csr_pk = (int*)((char*)d_ws + base + 1024);
    if (ws_size < base + 1024 + (size_t)64 * PK_STRIDE * 4) return;

    hipLaunchKernelGGL(bsl_prep, dim3(10241), dim3(256), 0, stream,
                       x, blocks, xb, bb, row_idx, col_idx, counts, sched, csr_pk);
    hipLaunchKernelGGL(bsl_main, dim3(32, 32), dim3(256), 0, stream,
                       xb, bb, bias, counts, sched, csr_pk, y);
}

// Round 5
// 183.468 us; speedup vs baseline: 1.3839x; 1.1717x over previous
//
#include <hip/hip_runtime.h>

// ---------------------------------------------------------------------------
// Block-sparse linear  y = x @ W^T + bias  on MI355X (gfx950)
// Round 7: the r2 (58us) step structure VERBATIM -- A+B staged via
// global_load_lds into 24KB LDS, __syncthreads, 16 MFMA/wave, __syncthreads --
// with exactly ONE change: occupancy. Un-paired schedule (one rb per wg),
// grid 32nt x 64rb = 2048 wgs in LPT order, launch_bounds(256,6) -> 6
// resident wgs/CU (144KB LDS, 6x52 VGPR = 312 <= 512/SIMD) instead of r2's 4.
// Rationale (ledger): r2 step stalls ~78% on the vmcnt drain; 4 co-resident
// wgs cannot cover a 78% stall (need ~5); every attempt to restructure the
// step itself regressed (r3 fat-wg 95us, r4 fine-steps 77us, r5 no-LDS
// 132us, r6 A-direct+counted-vmcnt 92us). So raise the number of independent
// barrier groups per CU and change nothing else.
// XCD locality unchanged from r2: bid = nt + 32*rank -> XCD = nt&7.
// Predicted: main 42-48us, MfmaUtil 28-34%, Occ ~50%, conflicts 0.
// ---------------------------------------------------------------------------

typedef __attribute__((ext_vector_type(8))) short bf16x8;   // MFMA A/B frag
typedef __attribute__((ext_vector_type(8))) unsigned short u16x8;
typedef __attribute__((ext_vector_type(4))) float f32x4;     // MFMA C/D frag

#define N_ROWS 4096
#define IN_DIM 4096
#define OUT_DIM 4096
#define K_BLOCKS 1024
#define NT 128            // rows per workgroup (4 waves x 32 rows)
#define PK_STRIDE 256     // max blocks per row-block we store (realistic max ~35)

// fp32 -> bf16 round-to-nearest-even
__device__ static inline unsigned short f2bf(float f) {
    unsigned u = __float_as_uint(f);
    u += 0x7FFFu + ((u >> 16) & 1u);
    return (unsigned short)(u >> 16);
}

__device__ static inline void async_copy16(const void* g, void* l) {
    __builtin_amdgcn_global_load_lds(
        (const __attribute__((address_space(1))) void*)g,
        (__attribute__((address_space(3))) void*)l, 16, 0, 0);
}

// --- prep: convert x (16M f32) + blocks (4M f32) to bf16, AND build CSR ----
// Blocks 0..10239 convert (each thread 8 floats); block 10240 builds the
// CSR + descending-count (LPT) schedule. Unchanged from r4-r6 (verified).
__global__ void bsl_prep(const float* __restrict__ x,
                         const float* __restrict__ blocks,
                         unsigned short* __restrict__ xb,
                         unsigned short* __restrict__ bb,
                         const int* __restrict__ row_idx,
                         const int* __restrict__ col_idx,
                         int* __restrict__ counts,
                         int* __restrict__ sched,
                         int* __restrict__ csr_pk) {
    if (blockIdx.x == 10240) {
        __shared__ int cnt_s[64];
        __shared__ int sorted_s[64];
        const int t = threadIdx.x;
        if (t < 64) cnt_s[t] = 0;
        __syncthreads();
#pragma unroll
        for (int i = 0; i < 4; ++i) {
            const int k = t + i * 256;           // 0..1023
            const int r = row_idx[k];
            const int rank = atomicAdd(&cnt_s[r], 1);
            if (rank < PK_STRIDE) csr_pk[r * PK_STRIDE + rank] = (k << 6) | col_idx[k];
        }
        __syncthreads();
        if (t < 64) {
            const int mc = cnt_s[t];
            counts[t] = mc;
            int pos = 0;
            for (int j = 0; j < 64; ++j) {
                const int cj = cnt_s[j];
                pos += (cj > mc || (cj == mc && j < t)) ? 1 : 0;
            }
            sorted_s[pos] = t;                   // descending by count
        }
        __syncthreads();
        if (t < 64) sched[t] = sorted_s[t];      // heavy row-blocks first (LPT)
        return;
    }
    // ---- convert ----
    long t = (long)blockIdx.x * 256 + threadIdx.x;   // 0 .. 2621439 (8 floats each)
    const float4* src;
    unsigned short* dst;
    long off4;
    if (t < 2097152) {            // x region
        src = (const float4*)x;  dst = xb;  off4 = t * 2;
    } else {                      // blocks region
        src = (const float4*)blocks;  dst = bb;  off4 = (t - 2097152) * 2;
    }
    float4 a = src[off4];
    float4 b = src[off4 + 1];
    u16x8 v;
    v[0] = f2bf(a.x); v[1] = f2bf(a.y); v[2] = f2bf(a.z); v[3] = f2bf(a.w);
    v[4] = f2bf(b.x); v[5] = f2bf(b.y); v[6] = f2bf(b.z); v[7] = f2bf(b.w);
    *(u16x8*)(dst + off4 * 4) = v;
}

// --- main: r2 step structure, one rb per wg, 6 wgs/CU ----------------------
// LDS 16B-slot swizzle (r2-verified, 0 bank conflicts): phys_slot(row, cc) =
// row*8 + (cc ^ (row&7)); staging lane l maps to (row = ch*8 + l/8,
// cc = (l&7)^(l/8)) by pre-swizzling the GLOBAL source column
// (global_load_lds dest must be linear, base + lane*16); read side xors the
// logical chunk with m&7 (every fragment row has row&7 == m&7).
__global__ __launch_bounds__(256, 6) void bsl_main(
    const unsigned short* __restrict__ xb,   // [4096][4096] bf16
    const unsigned short* __restrict__ blk,  // [1024][64][64] bf16
    const float* __restrict__ bias,
    const int* __restrict__ counts,
    const int* __restrict__ sched,
    const int* __restrict__ csr_pk,
    float* __restrict__ y) {
    __shared__ unsigned short a_lds[NT * 64];   // 16 KB
    __shared__ unsigned short b_lds[64 * 64];   //  8 KB   (24 KB -> 6 wgs/CU)

    const int tid = threadIdx.x;
    const int w = tid >> 6;        // wave 0..3 -> rows [w*32, w*32+32)
    const int l = tid & 63;
    const int m = l & 15;          // MFMA lane coord
    const int q = l >> 4;          // quad
    const int nt = blockIdx.x;     // 32 n-tiles of 128 rows
    const int n0 = nt * NT;
    const int rb = sched[blockIdx.y];   // heavy row-blocks dispatched first
    const int cnt = counts[rb];

    // staging lane constants (pre-swizzled global source)
    const int srow = l >> 3;                    // 0..7
    const int scc  = (l & 7) ^ srow;            // swizzled col-chunk
    const int scol = scc * 8;
    const int xorv = m & 7;                     // read-side swizzle

    f32x4 acc[2][4];
#pragma unroll
    for (int r = 0; r < 2; ++r)
#pragma unroll
        for (int c = 0; c < 4; ++c) acc[r][c] = (f32x4){0.f, 0.f, 0.f, 0.f};

    for (int kk = 0; kk < cnt; ++kk) {
        const int pk = csr_pk[rb * PK_STRIDE + kk];
        const int k  = pk >> 6;
        const int ci = pk & 63;

        // stage A tile: 128x64 bf16 = 16 chunks of 1KB; wave w: chunks i*4+w
        const unsigned short* xrow =
            xb + (size_t)(n0 + srow) * IN_DIM + ci * 64 + scol;
#pragma unroll
        for (int i = 0; i < 4; ++i) {
            const int ch = i * 4 + w;
            async_copy16(xrow + (size_t)(ch * 8) * IN_DIM, a_lds + ch * 512);
        }
        // stage B tile: 64x64 bf16 = 8 chunks; wave w: chunks w, w+4
        const unsigned short* brow =
            blk + (size_t)k * 4096 + srow * 64 + scol;
#pragma unroll
        for (int i = 0; i < 2; ++i) {
            const int ch = i * 4 + w;
            async_copy16(brow + ch * 512, b_lds + ch * 512);
        }
        __syncthreads();   // drains vmcnt (global_load_lds) + barrier

#pragma unroll
        for (int s = 0; s < 2; ++s) {
            bf16x8 af[2], bfr[4];
            const int cc = (s * 4 + q) ^ xorv;
#pragma unroll
            for (int r = 0; r < 2; ++r) {
                const int row = w * 32 + r * 16 + m;
                af[r] = *(const bf16x8*)(a_lds + row * 64 + cc * 8);
            }
#pragma unroll
            for (int c = 0; c < 4; ++c) {
                const int row = c * 16 + m;
                bfr[c] = *(const bf16x8*)(b_lds + row * 64 + cc * 8);
            }
#pragma unroll
            for (int r = 0; r < 2; ++r)
#pragma unroll
                for (int c = 0; c < 4; ++c)
                    acc[r][c] = __builtin_amdgcn_mfma_f32_16x16x32_bf16(
                        af[r], bfr[c], acc[r][c], 0, 0, 0);
        }
        __syncthreads();   // protect LDS before next staging
    }

    // epilogue: C/D layout col=lane&15, row=q*4+e (harness-verified r1-r6);
    // cnt==0 row-blocks still write bias (acc stays zero).
    const int colbase = rb * 64;
#pragma unroll
    for (int c = 0; c < 4; ++c) {
        const float bv = bias[colbase + c * 16 + m];
#pragma unroll
        for (int r = 0; r < 2; ++r) {
            const int rowb = n0 + w * 32 + r * 16 + q * 4;
#pragma unroll
            for (int e = 0; e < 4; ++e) {
                y[(size_t)(rowb + e) * OUT_DIM + colbase + c * 16 + m] =
                    acc[r][c][e] + bv;
            }
        }
    }
}

// ---------------------------------------------------------------------------
extern "C" void kernel_launch(void* const* d_in, const int* in_sizes, int n_in,
                              void* d_out, int out_size, void* d_ws, size_t ws_size,
                              hipStream_t stream) {
    const float* x      = (const float*)d_in[0];
    const float* blocks = (const float*)d_in[1];
    const float* bias   = (const float*)d_in[2];
    const int* row_idx  = (const int*)d_in[3];
    const int* col_idx  = (const int*)d_in[4];
    float* y = (float*)d_out;

    // ws layout: x_bf16 (32MB) | blocks_bf16 (8MB) | counts(64) | sched(64) |
    //            pad | csr_pk (64*PK_STRIDE ints)
    const size_t base = 41943040u;   // 40 MB
    unsigned short* xb = (unsigned short*)d_ws;
    unsigned short* bb = xb + (size_t)N_ROWS * IN_DIM;
    int* counts = (int*)((char*)d_ws + base);
    int* sched  = counts + 64;
    int* csr_pk = (int*)((char*)d_ws + base + 1024);
    if (ws_size < base + 1024 + (size_t)64 * PK_STRIDE * 4) return;

    hipLaunchKernelGGL(bsl_prep, dim3(10241), dim3(256), 0, stream,
                       x, blocks, xb, bb, row_idx, col_idx, counts, sched, csr_pk);
    hipLaunchKernelGGL(bsl_main, dim3(32, 64), dim3(256), 0, stream,
                       xb, bb, bias, counts, sched, csr_pk, y);
}